// Round 20
// baseline (111.463 us; speedup 1.0000x reference)
//
#include <hip/hip_runtime.h>

typedef unsigned short u16;
typedef __bf16 bf16;
typedef bf16  bf16x8 __attribute__((ext_vector_type(8)));
typedef float f32x4  __attribute__((ext_vector_type(4)));

constexpr int Bc  = 2;
constexpr int Tc  = 2048;
constexpr int Dc  = 1024;
constexpr int Hc  = 16;
constexpr int HDc = 64;
constexpr int Mg  = Bc * Tc;   // 4096 tokens
constexpr int Kg  = Dc;        // 1024 reduction dim

// round-to-nearest-even f32 -> bf16 (finite inputs only)
__device__ inline u16 f2b(float f) {
    union { float f; unsigned u; } c; c.f = f;
    unsigned r = c.u + 0x7FFFu + ((c.u >> 16) & 1u);
    return (u16)(r >> 16);
}

__device__ inline float exp2_hw(float x) {
    float r; asm("v_exp_f32 %0, %1" : "=v"(r) : "v"(x)); return r;
}
__device__ inline unsigned cvt_pk(float a, float b) {
    unsigned r; asm("v_cvt_pk_bf16_f32 %0, %1, %2" : "=v"(r) : "v"(a), "v"(b)); return r;
}
__device__ inline void gload16(const u16* g, u16* l) {
    __builtin_amdgcn_global_load_lds(
        (const __attribute__((address_space(1))) void*)g,
        (__attribute__((address_space(3))) void*)l, 16, 0, 0);
}

// ---------------- fused fp32 -> bf16 conversion (all 5 tensors, 1 launch) --------
struct CvtArgs { const float* src[5]; u16* dst[5]; int n[5]; };

__global__ __launch_bounds__(256) void cvt_all(CvtArgs a) {
    const int tid = blockIdx.x * blockDim.x + threadIdx.x;
    const int stride = gridDim.x * blockDim.x * 4;
    #pragma unroll
    for (int r = 0; r < 5; ++r) {
        const float* s = a.src[r];
        u16* d = a.dst[r];
        const int n = a.n[r];
        for (int i = tid * 4; i < n; i += stride) {
            float4 v = *reinterpret_cast<const float4*>(s + i);
            ushort4 o;
            o.x = f2b(v.x); o.y = f2b(v.y); o.z = f2b(v.z); o.w = f2b(v.w);
            *reinterpret_cast<ushort4*>(d + i) = o;
        }
    }
}

// ---------------- GEMM: C[M,N] = A[M,K] * W[N,K]^T (zero-phase, 64-row m-tiles) --
// Latency-bound at 3 blocks/CU (QKV) / 1 block/CU (proj): the per-K-step vmcnt(0)
// drain is hidden only by co-resident blocks. Halve m-tile to 64 rows -> QKV 1536
// blocks (6/CU), proj 512 (2/CU): doubled drain-overlap ways at equal total work.
// Wave layout 2m x 2n (32x64/wave, acc[2][4]); A staging drops to 1 gload16/wave.
// Swizzle f(row)=(row>>1)&3 for 64B rows (0 conflicts, r11/r16). XCD-grouped 1D
// remap extended: g = qq*8+rX (0..191 QKV / 0..63 proj), z=g>>6, m0=(g&63)*64.
template<int EPI>
__global__ __launch_bounds__(256) void gemm_bt(
    const u16* __restrict__ A,
    const u16* __restrict__ W0, const u16* __restrict__ W1, const u16* __restrict__ W2,
    u16* __restrict__ dQ, u16* __restrict__ dK, u16* __restrict__ dV,
    const float* __restrict__ bias, float* __restrict__ outF)
{
    __shared__ u16 As[64 * 32];
    __shared__ u16 Bs[128 * 32];

    const int t    = threadIdx.x;
    const int bid  = blockIdx.x;
    const int rX   = bid & 7;
    const int xblk = (bid >> 3) & 7;
    const int qq   = bid >> 6;
    const int g    = qq * 8 + rX;        // EPI=0: 0..191 ; EPI=1: 0..63
    const int z    = g >> 6;             // EPI=0: 0..2   ; EPI=1: 0
    const int m0   = (g & 63) * 64;
    const int n0   = xblk * 128;
    const u16* Wsel = (z == 0) ? W0 : (z == 1) ? W1 : W2;

    const int lane = t & 63, wave = t >> 6;
    const int wm = wave >> 1, wn = wave & 1;
    const int lo = lane & 15, hi = lane >> 4;

    f32x4 acc[2][4];
    const f32x4 fzero = {0.f, 0.f, 0.f, 0.f};
    #pragma unroll
    for (int i = 0; i < 2; ++i)
        #pragma unroll
        for (int j = 0; j < 4; ++j) acc[i][j] = fzero;

    const int rA = t >> 2;                              // 0..63
    const int ks = ((t & 3) ^ ((rA >> 1) & 3)) * 8;     // swizzle for 64B rows
    const u16* gA0 = A    + (size_t)(m0 + rA) * Kg + ks;
    const u16* gB0 = Wsel + (size_t)(n0 + rA) * Kg + ks;
    const u16* gB1 = gB0 + 64 * Kg;
    u16* lA0 = &As[(wave * 16) * 32];
    u16* lB0 = &Bs[(wave * 16) * 32];
    u16* lB1 = &Bs[(64 + wave * 16) * 32];

    const int sl = (hi ^ ((lo >> 1) & 3)) * 8;          // read-side swizzle

    for (int k0 = 0; k0 < Kg; k0 += 32) {
        __syncthreads();
        gload16(gA0 + k0, lA0);
        gload16(gB0 + k0, lB0);
        gload16(gB1 + k0, lB1);
        __syncthreads();

        bf16x8 af[2], bfr[4];
        #pragma unroll
        for (int fi = 0; fi < 2; ++fi)
            af[fi] = *reinterpret_cast<const bf16x8*>(&As[(wm * 32 + fi * 16 + lo) * 32 + sl]);
        #pragma unroll
        for (int fj = 0; fj < 4; ++fj)
            bfr[fj] = *reinterpret_cast<const bf16x8*>(&Bs[(wn * 64 + fj * 16 + lo) * 32 + sl]);
        #pragma unroll
        for (int fi = 0; fi < 2; ++fi)
            #pragma unroll
            for (int fj = 0; fj < 4; ++fj)
                acc[fi][fj] = __builtin_amdgcn_mfma_f32_16x16x32_bf16(af[fi], bfr[fj], acc[fi][fj], 0, 0, 0);
    }

    #pragma unroll
    for (int fi = 0; fi < 2; ++fi) {
        #pragma unroll
        for (int fj = 0; fj < 4; ++fj) {
            const int nn = n0 + wn * 64 + fj * 16 + lo;
            if constexpr (EPI == 0) {
                const int b = m0 >> 11;
                const int h = nn >> 6, hd = nn & 63;
                if (z == 2) {
                    const int tt0 = (m0 & (Tc - 1)) + wm * 32 + fi * 16 + hi * 4;
                    const int tile = tt0 >> 6;
                    const int k6   = tt0 & 63;
                    const int slot = ((k6 & 32) >> 3) + ((k6 & 15) >> 2);
                    const int halfE = (k6 & 16) >> 2;            // 0 or 4 elems
                    const size_t off =
                        (((size_t)(b * Hc + h) * 32 + tile) * 64 + hd) * 64 + slot * 8 + halfE;
                    ushort4 pv;
                    pv.x = f2b(acc[fi][fj][0]); pv.y = f2b(acc[fi][fj][1]);
                    pv.z = f2b(acc[fi][fj][2]); pv.w = f2b(acc[fi][fj][3]);
                    *reinterpret_cast<ushort4*>(&dV[off]) = pv;
                } else {
                    u16* dst = (z == 0) ? dQ : dK;
                    #pragma unroll
                    for (int r = 0; r < 4; ++r) {
                        const int m = m0 + wm * 32 + fi * 16 + hi * 4 + r;
                        const int tt = m & (Tc - 1);
                        dst[((((b * Hc + h) << 11) + tt) * HDc) + hd] = f2b(acc[fi][fj][r]);
                    }
                }
            } else {
                #pragma unroll
                for (int r = 0; r < 4; ++r) {
                    const int m = m0 + wm * 32 + fi * 16 + hi * 4 + r;
                    outF[(size_t)m * Dc + nn] = acc[fi][fj][r] + bias[nn];
                }
            }
        }
    }
}

// ---------------- causal flash attention (r18-exact: best measured, 41.4 µs) -----
// 512 thr / 8 waves; block bi owns consecutive pairs p = 4*bi + j, key parity c.
// NT = 32 - bi uniform in block. XCD-grouped 1D grid. setprio / stride-17 banned.
__global__ __launch_bounds__(512, 4) void attn_kernel(const u16* __restrict__ Q,
                                                      const u16* __restrict__ Kk,
                                                      const u16* __restrict__ Vp,
                                                      u16* __restrict__ O)
{
    __shared__ u16 Kl[2][64][64];   // 16 KB
    __shared__ u16 Vl[2][64][64];   // 16 KB
    float* Ob = (float*)&Kl[0][0][0];   // [4][64][16] floats = 16 KB
    float* Mb = (float*)&Vl[0][0][0];   // [4][16]
    float* Lb = Mb + 64;                // [4][16]

    const int t = threadIdx.x;
    const int w = t >> 6;
    const int lane = t & 63;
    const int j = w >> 1, c = w & 1;
    const int lo = lane & 15, hi = lane >> 4;
    const int l8 = lane >> 3, l7 = lane & 7;
    const int pb  = blockIdx.x;                 // 0..511
    const int xcd = pb & 7;
    const int kk  = pb >> 3;                    // 0..63
    const int bh  = xcd * 4 + (kk >> 4);        // 4 bh per XCD
    const int bi  = kk & 15;                    // 0..15
    const int p  = 4 * bi + j;                  // consecutive pairs 0..63
    const int ql0 = 16 * p;
    const int qh0 = 16 * (127 - p);
    const int NT  = 32 - bi;                    // uniform: covers qh0_max+15

    const u16* Qp = Q  + (size_t)bh * Tc * HDc;
    const u16* Kp = Kk + (size_t)bh * Tc * HDc;
    const u16* Vq = Vp + (size_t)bh * Tc * HDc;   // permuted panel image

    const float sc2 = 0.125f * 1.44269504f;
    const f32x4 fzero = {0.f, 0.f, 0.f, 0.f};

    bf16x8 qfl[2], qfh[2];
    #pragma unroll
    for (int h = 0; h < 2; ++h) {
        union { bf16x8 v; u16 u[8]; } a2, r2;
        a2.v = *reinterpret_cast<const bf16x8*>(Qp + (ql0 + lo) * HDc + 32 * h + 8 * hi);
        #pragma unroll
        for (int jj = 0; jj < 8; ++jj) {
            union { float f; unsigned u; } cc; cc.u = ((unsigned)a2.u[jj]) << 16;
            r2.u[jj] = f2b(cc.f * sc2);
        }
        qfl[h] = r2.v;
        a2.v = *reinterpret_cast<const bf16x8*>(Qp + (qh0 + lo) * HDc + 32 * h + 8 * hi);
        #pragma unroll
        for (int jj = 0; jj < 8; ++jj) {
            union { float f; unsigned u; } cc; cc.u = ((unsigned)a2.u[jj]) << 16;
            r2.u[jj] = f2b(cc.f * sc2);
        }
        qfh[h] = r2.v;
    }

    f32x4 ol[4], oh[4];
    float ml = -__builtin_inff(), mh = -__builtin_inff();
    float ll = 0.f, lh = 0.f;
    #pragma unroll
    for (int d = 0; d < 4; ++d) { ol[d] = fzero; oh[d] = fzero; }

    const int rb = 8 * w;
    const int swz = (l7 ^ l8) * 8;
    auto stage = [&](int tile, int b) {
        const u16* ksrc = Kp + (size_t)(tile * 64 + rb + l8) * 64 + swz;
        const u16* vsrc = Vq + (size_t)(tile * 64 + rb + l8) * 64 + swz;
        gload16(ksrc, &Kl[b][rb][0]);
        gload16(vsrc, &Vl[b][rb][0]);
    };

    auto step16 = [&](int kb, int q0v, const bf16x8 (&qv)[2], f32x4 (&o)[4],
                      float& m2, float& l2,
                      const bf16x8 (&kf)[2][2], const bf16x8 (&vf)[4]) {
        f32x4 s0, s1;
        s0 = __builtin_amdgcn_mfma_f32_16x16x32_bf16(kf[0][0], qv[0], fzero, 0, 0, 0);
        s0 = __builtin_amdgcn_mfma_f32_16x16x32_bf16(kf[0][1], qv[1], s0, 0, 0, 0);
        s1 = __builtin_amdgcn_mfma_f32_16x16x32_bf16(kf[1][0], qv[0], fzero, 0, 0, 0);
        s1 = __builtin_amdgcn_mfma_f32_16x16x32_bf16(kf[1][1], qv[1], s1, 0, 0, 0);

        if (kb + 31 > q0v) {
            const int q = q0v + lo;
            #pragma unroll
            for (int r = 0; r < 4; ++r) {
                if (kb + 4 * hi + r > q)      s0[r] = -__builtin_inff();
                if (kb + 16 + 4 * hi + r > q) s1[r] = -__builtin_inff();
            }
        }

        const float lmax = fmaxf(
            fmaxf(fmaxf(s0[0], s0[1]), fmaxf(s0[2], s0[3])),
            fmaxf(fmaxf(s1[0], s1[1]), fmaxf(s1[2], s1[3])));

        if (!__all(lmax <= m2 + 11.5f)) {
            float tmx = lmax;
            tmx = fmaxf(tmx, __shfl_xor(tmx, 16));
            tmx = fmaxf(tmx, __shfl_xor(tmx, 32));
            const float mn = fmaxf(m2, tmx);
            const float aq = exp2_hw(m2 - mn);
            m2 = mn;
            l2 *= aq;
            float ar[4];
            #pragma unroll
            for (int r = 0; r < 4; ++r) ar[r] = __shfl(aq, 4 * hi + r);
            #pragma unroll
            for (int d = 0; d < 4; ++d)
                #pragma unroll
                for (int r = 0; r < 4; ++r) o[d][r] *= ar[r];
        }

        float pr[8];
        #pragma unroll
        for (int r = 0; r < 4; ++r) pr[r]     = exp2_hw(s0[r] - m2);
        #pragma unroll
        for (int r = 0; r < 4; ++r) pr[4 + r] = exp2_hw(s1[r] - m2);
        l2 += ((pr[0] + pr[1]) + (pr[2] + pr[3])) + ((pr[4] + pr[5]) + (pr[6] + pr[7]));
        union { bf16x8 v; unsigned wv[4]; } pk;
        pk.wv[0] = cvt_pk(pr[0], pr[1]);
        pk.wv[1] = cvt_pk(pr[2], pr[3]);
        pk.wv[2] = cvt_pk(pr[4], pr[5]);
        pk.wv[3] = cvt_pk(pr[6], pr[7]);
        #pragma unroll
        for (int d = 0; d < 4; ++d)
            o[d] = __builtin_amdgcn_mfma_f32_16x16x32_bf16(pk.v, vf[d], o[d], 0, 0, 0);
    };

    stage(0, 0);
    __syncthreads();

    for (int tt = 0; tt < NT; ++tt) {
        const int cur = tt & 1;
        if (tt + 1 < NT) stage(tt + 1, cur ^ 1);
        const int kb = (tt << 6) + 32 * c;

        const bool hAct = (kb <= qh0 + 15);
        const bool lAct = (kb <= ql0 + 15);
        if (hAct || lAct) {
            const int sw = lo & 7;
            bf16x8 kf[2][2];
            #pragma unroll
            for (int kt = 0; kt < 2; ++kt)
                #pragma unroll
                for (int h = 0; h < 2; ++h)
                    kf[kt][h] = *reinterpret_cast<const bf16x8*>(
                        &Kl[cur][32 * c + 16 * kt + lo][((4 * h + hi) ^ sw) * 8]);
            bf16x8 vf[4];
            #pragma unroll
            for (int d = 0; d < 4; ++d)
                vf[d] = *reinterpret_cast<const bf16x8*>(
                    &Vl[cur][16 * d + lo][((4 * c + hi) ^ sw) * 8]);

            if (hAct) step16(kb, qh0, qfh, oh, mh, lh, kf, vf);
            if (lAct) step16(kb, ql0, qfl, ol, ml, ll, kf, vf);
        }
        __syncthreads();
    }

    const int b = bh >> 4, h = bh & 15;
    #pragma unroll
    for (int ph = 0; ph < 2; ++ph) {
        const f32x4* om = (ph == 0) ? oh : ol;
        const float  mm = (ph == 0) ? mh : ml;
        const float  lm = (ph == 0) ? lh : ll;
        const int    q0 = (ph == 0) ? qh0 : ql0;

        if (c == 1) {
            float lt = lm;
            lt += __shfl_xor(lt, 16);
            lt += __shfl_xor(lt, 32);
            if (hi == 0) { Mb[j * 16 + lo] = mm; Lb[j * 16 + lo] = lt; }
            float* op = Ob + (j * 64 + lane) * 16;
            #pragma unroll
            for (int d = 0; d < 4; ++d)
                #pragma unroll
                for (int r = 0; r < 4; ++r) op[d * 4 + r] = om[d][r];
        }
        __syncthreads();
        if (c == 0) {
            float lt = lm;
            lt += __shfl_xor(lt, 16);
            lt += __shfl_xor(lt, 32);
            const float m1 = Mb[j * 16 + lo];
            const float l1 = Lb[j * 16 + lo];
            const float M  = fmaxf(mm, m1);
            const float e0 = exp2_hw(mm - M);
            const float e1 = exp2_hw(m1 - M);
            const float Li = 1.0f / (lt * e0 + l1 * e1);
            float e0r[4], e1r[4], Lir[4];
            #pragma unroll
            for (int r = 0; r < 4; ++r) {
                e0r[r] = __shfl(e0, 4 * hi + r);
                e1r[r] = __shfl(e1, 4 * hi + r);
                Lir[r] = __shfl(Li, 4 * hi + r);
            }
            const float* op = Ob + (j * 64 + lane) * 16;
            #pragma unroll
            for (int d = 0; d < 4; ++d)
                #pragma unroll
                for (int r = 0; r < 4; ++r) {
                    const int q = q0 + 4 * hi + r;
                    const float val = (om[d][r] * e0r[r] + op[d * 4 + r] * e1r[r]) * Lir[r];
                    O[(size_t)(b * Tc + q) * Dc + h * 64 + 16 * d + lo] = f2b(val);
                }
        }
        __syncthreads();
    }
}

// ---------------- host launcher ----------------
extern "C" void kernel_launch(void* const* d_in, const int* in_sizes, int n_in,
                              void* d_out, int out_size, void* d_ws, size_t ws_size,
                              hipStream_t stream) {
    (void)in_sizes; (void)n_in; (void)out_size; (void)ws_size;
    const float* x  = (const float*)d_in[0];
    const float* Wk = (const float*)d_in[1];
    const float* Wq = (const float*)d_in[2];
    const float* Wv = (const float*)d_in[3];
    const float* Wp = (const float*)d_in[4];
    const float* bp = (const float*)d_in[5];
    float* out = (float*)d_out;

    char* ws = (char*)d_ws;
    u16* xb   = (u16*)(ws);
    u16* wqb  = (u16*)(ws + (8u  << 20));
    u16* wkb  = (u16*)(ws + (10u << 20));
    u16* wvb  = (u16*)(ws + (12u << 20));
    u16* wpb  = (u16*)(ws + (14u << 20));
    u16* Qb   = (u16*)(ws + (16u << 20));
    u16* Kb   = (u16*)(ws + (24u << 20));
    u16* Vtb  = (u16*)(ws + (32u << 20));   // permuted V panels
    u16* attb = (u16*)(ws + (40u << 20));

    CvtArgs ca;
    ca.src[0] = x;  ca.dst[0] = xb;  ca.n[0] = Mg * Dc;
    ca.src[1] = Wq; ca.dst[1] = wqb; ca.n[1] = Dc * Dc;
    ca.src[2] = Wk; ca.dst[2] = wkb; ca.n[2] = Dc * Dc;
    ca.src[3] = Wv; ca.dst[3] = wvb; ca.n[3] = Dc * Dc;
    ca.src[4] = Wp; ca.dst[4] = wpb; ca.n[4] = Dc * Dc;
    cvt_all<<<dim3(1024), 256, 0, stream>>>(ca);

    gemm_bt<0><<<dim3(1536), 256, 0, stream>>>(
        xb, wqb, wkb, wvb, Qb, Kb, Vtb, nullptr, nullptr);

    attn_kernel<<<dim3(512), 512, 0, stream>>>(Qb, Kb, Vtb, attb);

    gemm_bt<1><<<dim3(512), 256, 0, stream>>>(
        attb, wpb, wpb, wpb, nullptr, nullptr, nullptr, bp, out);
}

// Round 21
// 100.046 us; speedup vs baseline: 1.1141x; 1.1141x over previous
//
#include <hip/hip_runtime.h>

typedef unsigned short u16;
typedef __bf16 bf16;
typedef bf16  bf16x8 __attribute__((ext_vector_type(8)));
typedef float f32x4  __attribute__((ext_vector_type(4)));

constexpr int Bc  = 2;
constexpr int Tc  = 2048;
constexpr int Dc  = 1024;
constexpr int Hc  = 16;
constexpr int HDc = 64;
constexpr int Mg  = Bc * Tc;   // 4096 tokens
constexpr int Kg  = Dc;        // 1024 reduction dim

// round-to-nearest-even f32 -> bf16 (finite inputs only)
__device__ inline u16 f2b(float f) {
    union { float f; unsigned u; } c; c.f = f;
    unsigned r = c.u + 0x7FFFu + ((c.u >> 16) & 1u);
    return (u16)(r >> 16);
}

__device__ inline float exp2_hw(float x) {
    float r; asm("v_exp_f32 %0, %1" : "=v"(r) : "v"(x)); return r;
}
__device__ inline unsigned cvt_pk(float a, float b) {
    unsigned r; asm("v_cvt_pk_bf16_f32 %0, %1, %2" : "=v"(r) : "v"(a), "v"(b)); return r;
}
__device__ inline void gload16(const u16* g, u16* l) {
    __builtin_amdgcn_global_load_lds(
        (const __attribute__((address_space(1))) void*)g,
        (__attribute__((address_space(3))) void*)l, 16, 0, 0);
}

// ---------------- fused fp32 -> bf16 conversion (all 5 tensors, 1 launch) --------
struct CvtArgs { const float* src[5]; u16* dst[5]; int n[5]; };

__global__ __launch_bounds__(256) void cvt_all(CvtArgs a) {
    const int tid = blockIdx.x * blockDim.x + threadIdx.x;
    const int stride = gridDim.x * blockDim.x * 4;
    #pragma unroll
    for (int r = 0; r < 5; ++r) {
        const float* s = a.src[r];
        u16* d = a.dst[r];
        const int n = a.n[r];
        for (int i = tid * 4; i < n; i += stride) {
            float4 v = *reinterpret_cast<const float4*>(s + i);
            ushort4 o;
            o.x = f2b(v.x); o.y = f2b(v.y); o.z = f2b(v.z); o.w = f2b(v.w);
            *reinterpret_cast<ushort4*>(d + i) = o;
        }
    }
}

// ---------------- GEMM: C[M,N] = A[M,K] * W[N,K]^T (r16-exact: BK=32 zero-phase) -
// Local optimum confirmed by bracketing: dbuf (r12 NaN, r13 -16%), BK=64 (r17
// -20%), 64-row m-tiles (r20 -24%) all lose; zero-phase BK=32 at 3 blocks/CU with
// implicit cross-block overlap is the keeper. Swizzle f(row)=(row>>1)&3 (0
// conflicts, r11/r16). XCD-grouped 1D remap: bid = qq*64 + xblk*8 + rX,
// g = qq*8+rX, (m,z) = (g&31, g>>5) — 8 x-blocks sharing an A panel on one XCD.
template<int EPI>
__global__ __launch_bounds__(256) void gemm_bt(
    const u16* __restrict__ A,
    const u16* __restrict__ W0, const u16* __restrict__ W1, const u16* __restrict__ W2,
    u16* __restrict__ dQ, u16* __restrict__ dK, u16* __restrict__ dV,
    const float* __restrict__ bias, float* __restrict__ outF)
{
    __shared__ u16 As[128 * 32];
    __shared__ u16 Bs[128 * 32];

    const int t    = threadIdx.x;
    const int bid  = blockIdx.x;
    const int rX   = bid & 7;
    const int xblk = (bid >> 3) & 7;
    const int qq   = bid >> 6;
    const int g    = qq * 8 + rX;        // EPI=0: 0..95 ; EPI=1: 0..31
    const int z    = g >> 5;             // EPI=0: 0..2  ; EPI=1: 0
    const int m0   = (g & 31) * 128;
    const int n0   = xblk * 128;
    const u16* Wsel = (z == 0) ? W0 : (z == 1) ? W1 : W2;

    const int lane = t & 63, wave = t >> 6;
    const int wm = wave >> 1, wn = wave & 1;
    const int lo = lane & 15, hi = lane >> 4;

    f32x4 acc[4][4];
    const f32x4 fzero = {0.f, 0.f, 0.f, 0.f};
    #pragma unroll
    for (int i = 0; i < 4; ++i)
        #pragma unroll
        for (int j = 0; j < 4; ++j) acc[i][j] = fzero;

    const int rA = t >> 2;
    const int ks = ((t & 3) ^ ((rA >> 1) & 3)) * 8;    // swizzle matched to 64B rows
    const u16* gA0 = A    + (size_t)(m0 + rA) * Kg + ks;
    const u16* gA1 = gA0 + 64 * Kg;
    const u16* gB0 = Wsel + (size_t)(n0 + rA) * Kg + ks;
    const u16* gB1 = gB0 + 64 * Kg;
    u16* lA0 = &As[(wave * 16) * 32];
    u16* lA1 = &As[(64 + wave * 16) * 32];
    u16* lB0 = &Bs[(wave * 16) * 32];
    u16* lB1 = &Bs[(64 + wave * 16) * 32];

    const int sl = (hi ^ ((lo >> 1) & 3)) * 8;         // read-side: f(row)=(lo>>1)&3

    for (int k0 = 0; k0 < Kg; k0 += 32) {
        __syncthreads();
        gload16(gA0 + k0, lA0);
        gload16(gA1 + k0, lA1);
        gload16(gB0 + k0, lB0);
        gload16(gB1 + k0, lB1);
        __syncthreads();

        bf16x8 af[4], bfr[4];
        #pragma unroll
        for (int fi = 0; fi < 4; ++fi)
            af[fi] = *reinterpret_cast<const bf16x8*>(&As[(wm * 64 + fi * 16 + lo) * 32 + sl]);
        #pragma unroll
        for (int fj = 0; fj < 4; ++fj)
            bfr[fj] = *reinterpret_cast<const bf16x8*>(&Bs[(wn * 64 + fj * 16 + lo) * 32 + sl]);
        #pragma unroll
        for (int fi = 0; fi < 4; ++fi)
            #pragma unroll
            for (int fj = 0; fj < 4; ++fj)
                acc[fi][fj] = __builtin_amdgcn_mfma_f32_16x16x32_bf16(af[fi], bfr[fj], acc[fi][fj], 0, 0, 0);
    }

    #pragma unroll
    for (int fi = 0; fi < 4; ++fi) {
        #pragma unroll
        for (int fj = 0; fj < 4; ++fj) {
            const int nn = n0 + wn * 64 + fj * 16 + lo;
            if constexpr (EPI == 0) {
                const int b = m0 >> 11;
                const int h = nn >> 6, hd = nn & 63;
                if (z == 2) {
                    const int tt0 = (m0 & (Tc - 1)) + wm * 64 + fi * 16 + hi * 4;
                    const int tile = tt0 >> 6;
                    const int k6   = tt0 & 63;
                    const int slot = ((k6 & 32) >> 3) + ((k6 & 15) >> 2);
                    const int halfE = (k6 & 16) >> 2;            // 0 or 4 elems
                    const size_t off =
                        (((size_t)(b * Hc + h) * 32 + tile) * 64 + hd) * 64 + slot * 8 + halfE;
                    ushort4 pv;
                    pv.x = f2b(acc[fi][fj][0]); pv.y = f2b(acc[fi][fj][1]);
                    pv.z = f2b(acc[fi][fj][2]); pv.w = f2b(acc[fi][fj][3]);
                    *reinterpret_cast<ushort4*>(&dV[off]) = pv;
                } else {
                    u16* dst = (z == 0) ? dQ : dK;
                    #pragma unroll
                    for (int r = 0; r < 4; ++r) {
                        const int m = m0 + wm * 64 + fi * 16 + hi * 4 + r;
                        const int tt = m & (Tc - 1);
                        dst[((((b * Hc + h) << 11) + tt) * HDc) + hd] = f2b(acc[fi][fj][r]);
                    }
                }
            } else {
                #pragma unroll
                for (int r = 0; r < 4; ++r) {
                    const int m = m0 + wm * 64 + fi * 16 + hi * 4 + r;
                    outF[(size_t)m * Dc + nn] = acc[fi][fj][r] + bias[nn];
                }
            }
        }
    }
}

// ---------------- causal flash attention: consecutive-pair blocks (r18-exact) ----
// Best measured attn (41.4 µs). Block bi owns consecutive pairs p = 4*bi + j; wave
// 2j+c handles key parity c. NT = 32 - bi uniform in block (zero intra-block
// idling); cross-block imbalance absorbed by 2-rounds-per-CU greedy scheduling.
// XCD-grouped 1D grid (FETCH 68.7 -> 12.3 MB). setprio / stride-17 banned (NaN 2/2).
__global__ __launch_bounds__(512, 4) void attn_kernel(const u16* __restrict__ Q,
                                                      const u16* __restrict__ Kk,
                                                      const u16* __restrict__ Vp,
                                                      u16* __restrict__ O)
{
    __shared__ u16 Kl[2][64][64];   // 16 KB
    __shared__ u16 Vl[2][64][64];   // 16 KB
    // merge scratch aliases Kl/Vl (main loop fully done before use)
    float* Ob = (float*)&Kl[0][0][0];   // [4][64][16] floats = 16 KB
    float* Mb = (float*)&Vl[0][0][0];   // [4][16]
    float* Lb = Mb + 64;                // [4][16]

    const int t = threadIdx.x;
    const int w = t >> 6;
    const int lane = t & 63;
    const int j = w >> 1, c = w & 1;
    const int lo = lane & 15, hi = lane >> 4;
    const int l8 = lane >> 3, l7 = lane & 7;
    const int pb  = blockIdx.x;                 // 0..511
    const int xcd = pb & 7;
    const int kk  = pb >> 3;                    // 0..63
    const int bh  = xcd * 4 + (kk >> 4);        // 4 bh per XCD
    const int bi  = kk & 15;                    // 0..15
    const int p  = 4 * bi + j;                  // consecutive pairs 0..63
    const int ql0 = 16 * p;
    const int qh0 = 16 * (127 - p);
    const int NT  = 32 - bi;                    // uniform: covers qh0_max+15

    const u16* Qp = Q  + (size_t)bh * Tc * HDc;
    const u16* Kp = Kk + (size_t)bh * Tc * HDc;
    const u16* Vq = Vp + (size_t)bh * Tc * HDc;   // permuted panel image

    const float sc2 = 0.125f * 1.44269504f;
    const f32x4 fzero = {0.f, 0.f, 0.f, 0.f};

    // Q fragments (B-operand), prescaled into exp2 domain
    bf16x8 qfl[2], qfh[2];
    #pragma unroll
    for (int h = 0; h < 2; ++h) {
        union { bf16x8 v; u16 u[8]; } a2, r2;
        a2.v = *reinterpret_cast<const bf16x8*>(Qp + (ql0 + lo) * HDc + 32 * h + 8 * hi);
        #pragma unroll
        for (int jj = 0; jj < 8; ++jj) {
            union { float f; unsigned u; } cc; cc.u = ((unsigned)a2.u[jj]) << 16;
            r2.u[jj] = f2b(cc.f * sc2);
        }
        qfl[h] = r2.v;
        a2.v = *reinterpret_cast<const bf16x8*>(Qp + (qh0 + lo) * HDc + 32 * h + 8 * hi);
        #pragma unroll
        for (int jj = 0; jj < 8; ++jj) {
            union { float f; unsigned u; } cc; cc.u = ((unsigned)a2.u[jj]) << 16;
            r2.u[jj] = f2b(cc.f * sc2);
        }
        qfh[h] = r2.v;
    }

    f32x4 ol[4], oh[4];
    float ml = -__builtin_inff(), mh = -__builtin_inff();
    float ll = 0.f, lh = 0.f;
    #pragma unroll
    for (int d = 0; d < 4; ++d) { ol[d] = fzero; oh[d] = fzero; }

    // staging: wave w stages rows [8w,8w+8) of each 8KB tile (1 gload16 K + 1 V)
    const int rb = 8 * w;
    const int swz = (l7 ^ l8) * 8;              // pre-swizzled source slot
    auto stage = [&](int tile, int b) {
        const u16* ksrc = Kp + (size_t)(tile * 64 + rb + l8) * 64 + swz;
        const u16* vsrc = Vq + (size_t)(tile * 64 + rb + l8) * 64 + swz;
        gload16(ksrc, &Kl[b][rb][0]);
        gload16(vsrc, &Vl[b][rb][0]);
    };

    // one 32-key substep for one 16-row q-tile (shfl-free steady state)
    auto step16 = [&](int kb, int q0v, const bf16x8 (&qv)[2], f32x4 (&o)[4],
                      float& m2, float& l2,
                      const bf16x8 (&kf)[2][2], const bf16x8 (&vf)[4]) {
        f32x4 s0, s1;
        s0 = __builtin_amdgcn_mfma_f32_16x16x32_bf16(kf[0][0], qv[0], fzero, 0, 0, 0);
        s0 = __builtin_amdgcn_mfma_f32_16x16x32_bf16(kf[0][1], qv[1], s0, 0, 0, 0);
        s1 = __builtin_amdgcn_mfma_f32_16x16x32_bf16(kf[1][0], qv[0], fzero, 0, 0, 0);
        s1 = __builtin_amdgcn_mfma_f32_16x16x32_bf16(kf[1][1], qv[1], s1, 0, 0, 0);

        if (kb + 31 > q0v) {            // diagonal window: mask keys > q
            const int q = q0v + lo;
            #pragma unroll
            for (int r = 0; r < 4; ++r) {
                if (kb + 4 * hi + r > q)      s0[r] = -__builtin_inff();
                if (kb + 16 + 4 * hi + r > q) s1[r] = -__builtin_inff();
            }
        }

        const float lmax = fmaxf(
            fmaxf(fmaxf(s0[0], s0[1]), fmaxf(s0[2], s0[3])),
            fmaxf(fmaxf(s1[0], s1[1]), fmaxf(s1[2], s1[3])));

        if (!__all(lmax <= m2 + 11.5f)) {   // rescale path (rare)
            float tmx = lmax;
            tmx = fmaxf(tmx, __shfl_xor(tmx, 16));
            tmx = fmaxf(tmx, __shfl_xor(tmx, 32));
            const float mn = fmaxf(m2, tmx);
            const float aq = exp2_hw(m2 - mn);   // -inf -> 0 first time
            m2 = mn;
            l2 *= aq;
            float ar[4];
            #pragma unroll
            for (int r = 0; r < 4; ++r) ar[r] = __shfl(aq, 4 * hi + r);
            #pragma unroll
            for (int d = 0; d < 4; ++d)
                #pragma unroll
                for (int r = 0; r < 4; ++r) o[d][r] *= ar[r];
        }

        float pr[8];
        #pragma unroll
        for (int r = 0; r < 4; ++r) pr[r]     = exp2_hw(s0[r] - m2);
        #pragma unroll
        for (int r = 0; r < 4; ++r) pr[4 + r] = exp2_hw(s1[r] - m2);
        l2 += ((pr[0] + pr[1]) + (pr[2] + pr[3])) + ((pr[4] + pr[5]) + (pr[6] + pr[7]));
        union { bf16x8 v; unsigned wv[4]; } pk;
        pk.wv[0] = cvt_pk(pr[0], pr[1]);
        pk.wv[1] = cvt_pk(pr[2], pr[3]);
        pk.wv[2] = cvt_pk(pr[4], pr[5]);
        pk.wv[3] = cvt_pk(pr[6], pr[7]);
        #pragma unroll
        for (int d = 0; d < 4; ++d)
            o[d] = __builtin_amdgcn_mfma_f32_16x16x32_bf16(pk.v, vf[d], o[d], 0, 0, 0);
    };

    stage(0, 0);
    __syncthreads();

    for (int tt = 0; tt < NT; ++tt) {
        const int cur = tt & 1;
        if (tt + 1 < NT) stage(tt + 1, cur ^ 1);
        const int kb = (tt << 6) + 32 * c;      // this wave's parity half

        const bool hAct = (kb <= qh0 + 15);
        const bool lAct = (kb <= ql0 + 15);
        if (hAct || lAct) {
            const int sw = lo & 7;
            bf16x8 kf[2][2];
            #pragma unroll
            for (int kt = 0; kt < 2; ++kt)
                #pragma unroll
                for (int h = 0; h < 2; ++h)
                    kf[kt][h] = *reinterpret_cast<const bf16x8*>(
                        &Kl[cur][32 * c + 16 * kt + lo][((4 * h + hi) ^ sw) * 8]);
            bf16x8 vf[4];
            #pragma unroll
            for (int d = 0; d < 4; ++d)
                vf[d] = *reinterpret_cast<const bf16x8*>(
                    &Vl[cur][16 * d + lo][((4 * c + hi) ^ sw) * 8]);

            if (hAct) step16(kb, qh0, qfh, oh, mh, lh, kf, vf);
            if (lAct) step16(kb, ql0, qfl, ol, ml, ll, kf, vf);
        }
        __syncthreads();
    }

    // ---- parity merge (correct domains) + output: high tile then low tile ----
    const int b = bh >> 4, h = bh & 15;
    #pragma unroll
    for (int ph = 0; ph < 2; ++ph) {
        const f32x4* om = (ph == 0) ? oh : ol;          // my fragments
        const float  mm = (ph == 0) ? mh : ml;
        const float  lm = (ph == 0) ? lh : ll;
        const int    q0 = (ph == 0) ? qh0 : ql0;

        if (c == 1) {
            float lt = lm;                               // row-reduce partial l
            lt += __shfl_xor(lt, 16);
            lt += __shfl_xor(lt, 32);
            if (hi == 0) { Mb[j * 16 + lo] = mm; Lb[j * 16 + lo] = lt; }
            float* op = Ob + (j * 64 + lane) * 16;
            #pragma unroll
            for (int d = 0; d < 4; ++d)
                #pragma unroll
                for (int r = 0; r < 4; ++r) op[d * 4 + r] = om[d][r];
        }
        __syncthreads();
        if (c == 0) {
            float lt = lm;                               // my row l (indexed lo)
            lt += __shfl_xor(lt, 16);
            lt += __shfl_xor(lt, 32);
            const float m1 = Mb[j * 16 + lo];
            const float l1 = Lb[j * 16 + lo];
            const float M  = fmaxf(mm, m1);
            const float e0 = exp2_hw(mm - M);            // -inf-safe (mm finite)
            const float e1 = exp2_hw(m1 - M);            // m1 may be -inf -> 0
            const float Li = 1.0f / (lt * e0 + l1 * e1);
            float e0r[4], e1r[4], Lir[4];                // transpose S-row -> C-row
            #pragma unroll
            for (int r = 0; r < 4; ++r) {
                e0r[r] = __shfl(e0, 4 * hi + r);
                e1r[r] = __shfl(e1, 4 * hi + r);
                Lir[r] = __shfl(Li, 4 * hi + r);
            }
            const float* op = Ob + (j * 64 + lane) * 16;
            #pragma unroll
            for (int d = 0; d < 4; ++d)
                #pragma unroll
                for (int r = 0; r < 4; ++r) {
                    const int q = q0 + 4 * hi + r;
                    const float val = (om[d][r] * e0r[r] + op[d * 4 + r] * e1r[r]) * Lir[r];
                    O[(size_t)(b * Tc + q) * Dc + h * 64 + 16 * d + lo] = f2b(val);
                }
        }
        __syncthreads();
    }
}

// ---------------- host launcher ----------------
extern "C" void kernel_launch(void* const* d_in, const int* in_sizes, int n_in,
                              void* d_out, int out_size, void* d_ws, size_t ws_size,
                              hipStream_t stream) {
    (void)in_sizes; (void)n_in; (void)out_size; (void)ws_size;
    const float* x  = (const float*)d_in[0];
    const float* Wk = (const float*)d_in[1];
    const float* Wq = (const float*)d_in[2];
    const float* Wv = (const float*)d_in[3];
    const float* Wp = (const float*)d_in[4];
    const float* bp = (const float*)d_in[5];
    float* out = (float*)d_out;

    char* ws = (char*)d_ws;
    u16* xb   = (u16*)(ws);
    u16* wqb  = (u16*)(ws + (8u  << 20));
    u16* wkb  = (u16*)(ws + (10u << 20));
    u16* wvb  = (u16*)(ws + (12u << 20));
    u16* wpb  = (u16*)(ws + (14u << 20));
    u16* Qb   = (u16*)(ws + (16u << 20));
    u16* Kb   = (u16*)(ws + (24u << 20));
    u16* Vtb  = (u16*)(ws + (32u << 20));   // permuted V panels
    u16* attb = (u16*)(ws + (40u << 20));

    CvtArgs ca;
    ca.src[0] = x;  ca.dst[0] = xb;  ca.n[0] = Mg * Dc;
    ca.src[1] = Wq; ca.dst[1] = wqb; ca.n[1] = Dc * Dc;
    ca.src[2] = Wk; ca.dst[2] = wkb; ca.n[2] = Dc * Dc;
    ca.src[3] = Wv; ca.dst[3] = wvb; ca.n[3] = Dc * Dc;
    ca.src[4] = Wp; ca.dst[4] = wpb; ca.n[4] = Dc * Dc;
    cvt_all<<<dim3(1024), 256, 0, stream>>>(ca);

    gemm_bt<0><<<dim3(768), 256, 0, stream>>>(
        xb, wqb, wkb, wvb, Qb, Kb, Vtb, nullptr, nullptr);

    attn_kernel<<<dim3(512), 512, 0, stream>>>(Qb, Kb, Vtb, attb);

    gemm_bt<1><<<dim3(256), 256, 0, stream>>>(
        attb, wpb, wpb, wpb, nullptr, nullptr, nullptr, bp, out);
}